// Round 13
// baseline (305.175 us; speedup 1.0000x reference)
//
#include <hip/hip_runtime.h>
#include <hip/hip_fp16.h>

#define N_NODES 50000
#define N_EDGES 3200000
#define N_GRAPHS 50
#define IN_F 5
#define HID 64
#define OUT_F 2

#define BK2_SHIFT 7
#define BK2_W 128                      // nodes per bucket
#define NBKT2 391                      // ceil(50000/128)
#define NB1 250                        // phase-1 blocks
#define EPB 12800                      // edges per phase-1 block (250*12800 = 3.2M exact)
#define CAP2 9216                      // max edges/bucket (mean 8184, sigma ~90 -> +11 sigma)
#define NBIN2 128                      // sort bins (dst_local)
#define NWAVE 8192                     // k_h2g waves (2048 blocks, all co-resident)

// ---------- phase 1a: per-(bucket,block) histogram ----------
__global__ void k_bhist(const int* dst, unsigned short* cw) {
    __shared__ int hist[NBKT2];
    int t = threadIdx.x, blk = blockIdx.x;
    for (int b = t; b < NBKT2; b += 1024) hist[b] = 0;
    __syncthreads();
    int base = blk * EPB;
    for (int k = t; k < EPB; k += 1024)
        atomicAdd(&hist[dst[base + k] >> BK2_SHIFT], 1);
    __syncthreads();
    for (int b = t; b < NBKT2; b += 1024)
        cw[b * NB1 + blk] = (unsigned short)hist[b];
}

// ---------- phase 1b: per-bucket exclusive scan over the 250 block-counts ----------
__global__ void k_bscanA(unsigned short* cw, int* total) {
    __shared__ int s[256];
    int t = threadIdx.x, b = blockIdx.x;
    int v = (t < NB1) ? (int)cw[b * NB1 + t] : 0;
    s[t] = v;
    __syncthreads();
    for (int off = 1; off < 256; off <<= 1) {
        int a = (t >= off) ? s[t - off] : 0;
        __syncthreads();
        s[t] += a;
        __syncthreads();
    }
    if (t < NB1) cw[b * NB1 + t] = (unsigned short)(s[t] - v);  // in-place exclusive
    if (t == 255) total[b] = s[255];
}

// ---------- phase 1c: exclusive scan of 391 bucket totals -> rpB ----------
__global__ void k_bscanB(const int* total, int* rpB) {
    __shared__ int s[256];
    int t = threadIdx.x;
    int v[2], sum = 0;
#pragma unroll
    for (int j = 0; j < 2; ++j) {
        int idx = t * 2 + j;
        v[j] = (idx < NBKT2) ? total[idx] : 0;
        sum += v[j];
    }
    s[t] = sum;
    __syncthreads();
    for (int off = 1; off < 256; off <<= 1) {
        int a = (t >= off) ? s[t - off] : 0;
        __syncthreads();
        s[t] += a;
        __syncthreads();
    }
    int run = s[t] - sum;
#pragma unroll
    for (int j = 0; j < 2; ++j) {
        int idx = t * 2 + j;
        if (idx < NBKT2) rpB[idx] = run;
        run += v[j];
    }
    if (t == 0) rpB[NBKT2] = N_EDGES;
}

// ---------- phase 1d: deterministic scatter: key4 = src|dl7<<16, wh2 = fp16 w ----------
__global__ void k_bucket(const int* src, const int* dst, const float* ew,
                         const unsigned short* cw, const int* rpB,
                         int* key4, unsigned short* wh2) {
    __shared__ int base[NBKT2];
    __shared__ int off[NBKT2];
    int t = threadIdx.x, blk = blockIdx.x;
    for (int b = t; b < NBKT2; b += 1024) {
        base[b] = (int)cw[b * NB1 + blk] + rpB[b];
        off[b] = 0;
    }
    __syncthreads();
    int ebase = blk * EPB;
    for (int k = t; k < EPB; k += 1024) {
        int idx = ebase + k;
        int d = dst[idx];
        int b = d >> BK2_SHIFT;
        int sl = base[b] + atomicAdd(&off[b], 1);
        key4[sl] = src[idx] | ((d & (BK2_W - 1)) << 16);
        wh2[sl] = __half_as_ushort(__float2half(ew[idx]));
    }
}

// ---------- phase 2: 128-bin sort per bucket; emits pk (over key4), rp2, dinv, xp ----------
__global__ __launch_bounds__(1024) void k_bsort2(const int* rpB, int* key4,
                      const unsigned short* wh2, const float* x,
                      int* rp2, int* rp2e, float* dinv, __half* xp) {
    __shared__ int keybuf[CAP2];          // 36 KB
    __shared__ unsigned short whbuf[CAP2];// 18 KB
    __shared__ int hist[NBIN2];
    __shared__ int binoff[NBIN2];
    __shared__ int s[NBIN2];
    __shared__ float wd[NBIN2];
    int t = threadIdx.x, b = blockIdx.x;
    int e0 = rpB[b], cnt = rpB[b + 1] - e0;
    if (t < NBIN2) { hist[t] = 0; wd[t] = 0.f; }
    __syncthreads();
    for (int k = t; k < cnt; k += 1024) {
        int u = key4[e0 + k];
        unsigned short wh = wh2[e0 + k];
        keybuf[k] = u; whbuf[k] = wh;
        int dl = (u >> 16) & (BK2_W - 1);
        atomicAdd(&hist[dl], 1);
        atomicAdd(&wd[dl], __half2float(__ushort_as_half(wh)));
    }
    __syncthreads();
    if (t < NBIN2) s[t] = hist[t];
    __syncthreads();
    for (int off = 1; off < NBIN2; off <<= 1) {
        int a = (t < NBIN2 && t >= off) ? s[t - off] : 0;
        __syncthreads();
        if (t < NBIN2) s[t] += a;
        __syncthreads();
    }
    if (t < NBIN2) {
        binoff[t] = s[t] - hist[t];      // exclusive
        int node = (b << BK2_SHIFT) + t;
        if (node < N_NODES) {
            rp2[node]  = e0 + s[t] - hist[t];
            rp2e[node] = e0 + s[t];
            float di = rsqrtf(1.0f + wd[t]);
            dinv[node] = di;
            const float* xi = &x[node * IN_F];
            __half* o = &xp[node * 8];
#pragma unroll
            for (int f = 0; f < IN_F; ++f) o[f] = __float2half(xi[f] * di);
            o[5] = o[6] = o[7] = __float2half(0.f);
        }
    }
    __syncthreads();
    for (int k = t; k < cnt; k += 1024) {
        int u = keybuf[k];
        int dl = (u >> 16) & (BK2_W - 1);
        int pos = atomicAdd(&binoff[dl], 1);
        key4[e0 + pos] = (u & 0xFFFF) | ((int)whbuf[k] << 16);   // {src | fp16 w}
    }
}

// ---------- layer-1 gather: p = di*(sum w*xp[s] + xp[node]) ----------
__global__ void k_p(const int* rp2, const int* rp2e, const int* pk,
                    const __half* xp, const float* dinv, float* p) {
    int node = blockIdx.x * 4 + (threadIdx.x >> 6);
    int lane = threadIdx.x & 63;
    if (node >= N_NODES) return;
    int b = rp2[node], en = rp2e[node];
    float a0 = 0.f, a1 = 0.f, a2 = 0.f, a3 = 0.f, a4 = 0.f;
    for (int k = b + lane; k < en; k += 64) {
        int e = pk[k];
        float w = __half2float(__ushort_as_half((unsigned short)((unsigned)e >> 16)));
        const __half* xs = &xp[(e & 0xFFFF) * 8];
        int4 xv = *reinterpret_cast<const int4*>(xs);
        __half2 p01 = *(__half2*)&xv.x;
        __half2 p23 = *(__half2*)&xv.y;
        __half2 p45 = *(__half2*)&xv.z;
        a0 += w * __half2float(p01.x); a1 += w * __half2float(p01.y);
        a2 += w * __half2float(p23.x); a3 += w * __half2float(p23.y);
        a4 += w * __half2float(p45.x);
    }
    for (int off = 32; off; off >>= 1) {
        a0 += __shfl_down(a0, off); a1 += __shfl_down(a1, off); a2 += __shfl_down(a2, off);
        a3 += __shfl_down(a3, off); a4 += __shfl_down(a4, off);
    }
    if (lane == 0) {
        float di = dinv[node];
        const __half* xn = &xp[node * 8];
        float* pp = &p[node * IN_F];
        pp[0] = di * (a0 + __half2float(xn[0]));
        pp[1] = di * (a1 + __half2float(xn[1]));
        pp[2] = di * (a2 + __half2float(xn[2]));
        pp[3] = di * (a3 + __half2float(xn[3]));
        pp[4] = di * (a4 + __half2float(xn[4]));
    }
}

// ---------- fused h1 = relu(p@W1+b1); g' = (h1@W2)*dinv -> biased-u8/row + scale ----------
__global__ void k_h1g(const float* p, const float* W1, const float* b1,
                      const float* W2, const float* dinv,
                      unsigned char* g8u, float* rs) {
    __shared__ float W1s[IN_F * HID];
    __shared__ float W2s[HID * HID];
    __shared__ float b1s[HID];
    int t = threadIdx.x;
    for (int k = t; k < IN_F * HID; k += 256) W1s[k] = W1[k];
    for (int k = t; k < HID * HID; k += 256) W2s[k] = W2[k];
    if (t < HID) b1s[t] = b1[t];
    __syncthreads();
    int lane = t & 63;
    int wid = blockIdx.x * 4 + (t >> 6);
    int nw = gridDim.x * 4;
    for (int node = wid; node < N_NODES; node += nw) {
        const float* pp = &p[node * IN_F];
        float pv0 = pp[0], pv1 = pp[1], pv2 = pp[2], pv3 = pp[3], pv4 = pp[4];
        float h = b1s[lane] + pv0 * W1s[lane] + pv1 * W1s[64 + lane] + pv2 * W1s[128 + lane]
                + pv3 * W1s[192 + lane] + pv4 * W1s[256 + lane];
        h = fmaxf(h, 0.f);
        float acc = 0.f;
#pragma unroll
        for (int f = 0; f < HID; ++f) {
            float hf = __int_as_float(__builtin_amdgcn_readlane(__float_as_int(h), f));
            acc += hf * W2s[f * HID + lane];
        }
        float gv = acc * dinv[node];                 // g' value
        float am = fabsf(gv);
        for (int off = 32; off; off >>= 1) am = fmaxf(am, __shfl_xor(am, off));
        float inv = (am > 0.f) ? 127.0f / am : 0.f;
        g8u[node * HID + lane] = (unsigned char)(__float2int_rn(gv * inv) + 128);
        if (lane == 0) rs[node] = (am > 0.f) ? am * (1.0f / 127.0f) : 0.f;
    }
}

// ---------- layer-2: dword gather (4 feats/lane, 4 edges/wave) + bias/relu/pool ----------
#define EDGE4_BODY(UU)                                                         \
    {                                                                          \
        int u_ = (UU);                                                         \
        float w_ = __half2float(__ushort_as_half((unsigned short)((unsigned)u_ >> 16))); \
        float wwv_ = w_ * rs[u_ & 0xFFFF];                                     \
        unsigned dw_ = *(const unsigned*)&g8u[(u_ & 0xFFFF) * HID + fo];       \
        a0 += wwv_ * (float)(dw_ & 0xFF);                                      \
        a1 += wwv_ * (float)((dw_ >> 8) & 0xFF);                               \
        a2 += wwv_ * (float)((dw_ >> 16) & 0xFF);                              \
        a3 += wwv_ * (float)(dw_ >> 24);                                       \
        sww += wwv_;                                                           \
    }

__global__ __launch_bounds__(256, 8) void k_h2g(const int* rp2, const int* rp2e,
                      const int* pk, const float* dinv, const unsigned char* g8u,
                      const float* rs, const float* b2, const int* batch, float* pool) {
    int t = threadIdx.x, lane = t & 63;
    int grp = lane >> 4;                 // edge sub-group 0..3
    int fo = (lane & 15) << 2;           // feature offset 0..60
    int wid = blockIdx.x * 4 + (t >> 6);
    int n0 = (int)(((long long)wid * N_NODES) / NWAVE);
    int n1 = (int)(((long long)(wid + 1) * N_NODES) / NWAVE);
    if (n0 >= n1) return;
    float4 bj = *reinterpret_cast<const float4*>(&b2[fo]);
    float p0 = 0.f, p1 = 0.f, p2 = 0.f, p3 = 0.f;
    int cur = batch[n0];
    for (int node = n0; node < n1; ++node) {
        // self-loop, quarter-weighted (x4 across groups = exact)
        unsigned dws = *(const unsigned*)&g8u[node * HID + fo];
        float wq4 = 0.25f * rs[node];
        float a0 = wq4 * (float)(dws & 0xFF);
        float a1 = wq4 * (float)((dws >> 8) & 0xFF);
        float a2 = wq4 * (float)((dws >> 16) & 0xFF);
        float a3 = wq4 * (float)(dws >> 24);
        float sww = wq4;
        for (int k0 = rp2[node], e1 = rp2e[node]; k0 < e1; k0 += 64) {
            int kk = k0 + lane;
            int ev = (kk < e1) ? pk[kk] : 0;          // pad: src=0, w=+0.0
            int m = e1 - k0; if (m > 64) m = 64;
            if (m == 64) {
#pragma unroll
                for (int q = 0; q < 16; ++q) EDGE4_BODY(__shfl(ev, (q << 2) | grp))
            } else {
                int ng = (m + 3) >> 2;
                for (int q = 0; q < ng; ++q) EDGE4_BODY(__shfl(ev, (q << 2) | grp))
            }
        }
        // reduce across the 4 groups
#pragma unroll
        for (int off = 16; off <= 32; off <<= 1) {
            a0 += __shfl_xor(a0, off); a1 += __shfl_xor(a1, off);
            a2 += __shfl_xor(a2, off); a3 += __shfl_xor(a3, off);
            sww += __shfl_xor(sww, off);
        }
        float di = dinv[node];
        float corr = 128.0f * sww;
        float h0 = fmaxf(di * (a0 - corr) + bj.x, 0.f);
        float h1 = fmaxf(di * (a1 - corr) + bj.y, 0.f);
        float h2 = fmaxf(di * (a2 - corr) + bj.z, 0.f);
        float h3 = fmaxf(di * (a3 - corr) + bj.w, 0.f);
        int bb = batch[node];
        if (bb != cur) {
            if (lane < 16) {
                float* pb = &pool[cur * HID + fo];
                atomicAdd(pb + 0, p0); atomicAdd(pb + 1, p1);
                atomicAdd(pb + 2, p2); atomicAdd(pb + 3, p3);
            }
            cur = bb;
            p0 = p1 = p2 = p3 = 0.f;
        }
        p0 += h0; p1 += h1; p2 += h2; p3 += h3;
    }
    if (lane < 16) {
        float* pb = &pool[cur * HID + fo];
        atomicAdd(pb + 0, p0); atomicAdd(pb + 1, p1);
        atomicAdd(pb + 2, p2); atomicAdd(pb + 3, p3);
    }
}

__device__ int lowb(const int* a, int n, int v) {
    int lo = 0, hi = n;
    while (lo < hi) { int m = (lo + hi) >> 1; if (a[m] < v) lo = m + 1; else hi = m; }
    return lo;
}

__global__ void k_out(const float* pool, const int* batch, const float* Wo,
                      const float* bo, float* out) {
    int t = blockIdx.x * blockDim.x + threadIdx.x;
    if (t < N_GRAPHS * OUT_F) {
        int gi = t / OUT_F, k = t % OUT_F;
        int c = lowb(batch, N_NODES, gi + 1) - lowb(batch, N_NODES, gi);
        float cf = fmaxf((float)c, 1.0f);
        float acc = bo[k];
        for (int f = 0; f < HID; ++f)
            acc += (pool[gi * HID + f] / cf) * Wo[f * OUT_F + k];
        out[t] = acc;
    }
}

extern "C" void kernel_launch(void* const* d_in, const int* in_sizes, int n_in,
                              void* d_out, int out_size, void* d_ws, size_t ws_size,
                              hipStream_t stream) {
    const float* x   = (const float*)d_in[0];
    const int*   ei  = (const int*)d_in[1];
    const float* ea  = (const float*)d_in[2];
    const int*   bat = (const int*)d_in[3];
    const float* W1  = (const float*)d_in[4];
    const float* b1  = (const float*)d_in[5];
    const float* W2  = (const float*)d_in[6];
    const float* b2  = (const float*)d_in[7];
    const float* Wo  = (const float*)d_in[8];
    const float* bo  = (const float*)d_in[9];
    float* out = (float*)d_out;

    const int* src = ei;
    const int* dst = ei + N_EDGES;

    // workspace layout (float units) — total 6,253,664 floats = 25.0 MB
    float* ws = (float*)d_ws;
    int*   rpB   = (int*)ws;                         // 392 (pad 400)
    int*   rp2   = (int*)(ws + 400);                 // 50000 (pad 50016)
    int*   rp2e  = (int*)(ws + 50416);               // 50000 (pad 50016)
    float* dinv  = ws + 100432;                      // 50000 (pad 50016)
    float* rs    = ws + 150448;                      // 50000 (pad 50016)
    float* pool  = ws + 200464;                      // 3200
    int*   total = (int*)(ws + 200464);              // 391, overlays pool, dead after bscanB
    float* p     = ws + 203664;                      // 250000
    unsigned short* cw = (unsigned short*)(ws + 203664);  // 97750 u16 overlays p, dead after k_bucket
    int*   key4  = (int*)(ws + 453664);              // 3.2M ints; becomes packed pk after k_bsort2
    unsigned short* wh2 = (unsigned short*)(ws + 3653664);  // 3.2M u16 = 1.6M floats
    unsigned char* g8u = (unsigned char*)(ws + 5253664);    // 3.2MB = 800000 floats
    __half* xp   = (__half*)(ws + 6053664);          // 400000 halves = 200000 floats

    k_bhist <<<NB1, 1024, 0, stream>>>(dst, cw);
    k_bscanA<<<NBKT2, 256, 0, stream>>>(cw, total);
    k_bscanB<<<1, 256, 0, stream>>>(total, rpB);
    hipMemsetAsync(pool, 0, N_GRAPHS * HID * sizeof(float), stream);  // after bscanB (total overlays pool)
    k_bucket<<<NB1, 1024, 0, stream>>>(src, dst, ea, cw, rpB, key4, wh2);
    k_bsort2<<<NBKT2, 1024, 0, stream>>>(rpB, key4, wh2, x, rp2, rp2e, dinv, xp);
    k_p     <<<(N_NODES + 3) / 4, 256, 0, stream>>>(rp2, rp2e, key4, xp, dinv, p);
    k_h1g   <<<1024, 256, 0, stream>>>(p, W1, b1, W2, dinv, g8u, rs);
    k_h2g   <<<NWAVE / 4, 256, 0, stream>>>(rp2, rp2e, key4, dinv, g8u, rs, b2, bat, pool);
    k_out   <<<1, 128, 0, stream>>>(pool, bat, Wo, bo, out);
}

// Round 14
// 288.241 us; speedup vs baseline: 1.0587x; 1.0587x over previous
//
#include <hip/hip_runtime.h>
#include <hip/hip_fp16.h>

#define N_NODES 50000
#define N_EDGES 3200000
#define N_GRAPHS 50
#define IN_F 5
#define HID 64
#define OUT_F 2

#define BK2_SHIFT 7
#define BK2_W 128                      // nodes per bucket
#define NBKT2 391                      // ceil(50000/128)
#define NB1 250                        // phase-1 blocks
#define EPB 12800                      // edges per phase-1 block (250*12800 = 3.2M exact)
#define TILE 6400                      // edges staged in LDS per pass
#define SLOTS 7                        // ceil(TILE/1024)
#define CAP2 9216                      // max edges/bucket (mean 8192, sigma ~90 -> +11 sigma)
#define NBIN2 128                      // sort bins (dst_local)
#define NWAVE 8192                     // k_h2g waves (2048 blocks, all co-resident)

// ---------- global per-bucket totals (LDS-aggregated histogram) ----------
__global__ __launch_bounds__(1024) void k_bhist(const int* dst, int* total) {
    __shared__ int hist[NBKT2];
    int t = threadIdx.x, blk = blockIdx.x;
    for (int b = t; b < NBKT2; b += 1024) hist[b] = 0;
    __syncthreads();
    int base = blk * EPB;
    for (int k = t; k < EPB; k += 1024)
        atomicAdd(&hist[__builtin_nontemporal_load(&dst[base + k]) >> BK2_SHIFT], 1);
    __syncthreads();
    for (int b = t; b < NBKT2; b += 1024) {
        int h = hist[b];
        if (h) atomicAdd(&total[b], h);
    }
}

// ---------- exclusive scan of 391 totals -> rpB, cursor ----------
__global__ void k_bscanB(const int* total, int* rpB, int* cursor) {
    __shared__ int s[256];
    int t = threadIdx.x;
    int v[2], sum = 0;
#pragma unroll
    for (int j = 0; j < 2; ++j) {
        int idx = t * 2 + j;
        v[j] = (idx < NBKT2) ? total[idx] : 0;
        sum += v[j];
    }
    s[t] = sum;
    __syncthreads();
    for (int off = 1; off < 256; off <<= 1) {
        int a = (t >= off) ? s[t - off] : 0;
        __syncthreads();
        s[t] += a;
        __syncthreads();
    }
    int run = s[t] - sum;
#pragma unroll
    for (int j = 0; j < 2; ++j) {
        int idx = t * 2 + j;
        if (idx < NBKT2) { rpB[idx] = run; cursor[idx] = run; }
        run += v[j];
    }
    if (t == 0) rpB[NBKT2] = N_EDGES;
}

// ---------- LDS-staged bucket scatter: burst-contiguous chunk writes ----------
// key = src | dst<<16 (both < 65536); chunk per (bucket,tile) reserved via 1 atomic
__global__ __launch_bounds__(1024) void k_bucket(const int* src, const int* dst,
                        const float* ew, int* cursor, int* key4, unsigned short* wh2) {
    __shared__ int keyb[TILE];             // 25.6 KB
    __shared__ unsigned short whb[TILE];   // 12.8 KB
    __shared__ int hist[NBKT2];
    __shared__ int soff[NBKT2];
    __shared__ int delta[NBKT2];
    __shared__ int s[512];
    int t = threadIdx.x, blk = blockIdx.x;
    for (int tile = 0; tile < EPB / TILE; ++tile) {
        int base = blk * EPB + tile * TILE;
        for (int b = t; b < NBKT2; b += 1024) hist[b] = 0;
        __syncthreads();
        int ky[SLOTS]; unsigned short wv[SLOTS]; int rk[SLOTS];
#pragma unroll
        for (int i = 0; i < SLOTS; ++i) {
            int k = t + i * 1024;
            if (k < TILE) {
                int d  = __builtin_nontemporal_load(&dst[base + k]);
                int sv = __builtin_nontemporal_load(&src[base + k]);
                float w = __builtin_nontemporal_load(&ew[base + k]);
                ky[i] = sv | (d << 16);
                wv[i] = __half_as_ushort(__float2half(w));
                rk[i] = atomicAdd(&hist[d >> BK2_SHIFT], 1);
            }
        }
        __syncthreads();
        if (t < 512) s[t] = (t < NBKT2) ? hist[t] : 0;
        __syncthreads();
        for (int off = 1; off < 512; off <<= 1) {
            int a = (t < 512 && t >= off) ? s[t - off] : 0;
            __syncthreads();
            if (t < 512) s[t] += a;
            __syncthreads();
        }
        if (t < NBKT2) {
            int h = hist[t];
            soff[t] = s[t] - h;                       // tile-local exclusive offset
            if (h) delta[t] = atomicAdd(&cursor[t], h) - soff[t];
        }
        __syncthreads();
#pragma unroll
        for (int i = 0; i < SLOTS; ++i) {
            int k = t + i * 1024;
            if (k < TILE) {
                int b = ((unsigned)ky[i] >> 16) >> BK2_SHIFT;
                int p = soff[b] + rk[i];
                keyb[p] = ky[i];
                whb[p] = wv[i];
            }
        }
        __syncthreads();
#pragma unroll
        for (int i = 0; i < SLOTS; ++i) {
            int k = t + i * 1024;
            if (k < TILE) {
                int u = keyb[k];
                int b = ((unsigned)u >> 16) >> BK2_SHIFT;
                int gp = k + delta[b];
                key4[gp] = u;
                wh2[gp] = whb[k];
            }
        }
        __syncthreads();
    }
}

// ---------- phase 2: 128-bin sort per bucket; emits pk (over key4), rp2, dinv, xp ----------
__global__ __launch_bounds__(1024) void k_bsort2(const int* rpB, int* key4,
                      const unsigned short* wh2, const float* x,
                      int* rp2, int* rp2e, float* dinv, __half* xp) {
    __shared__ int keybuf[CAP2];          // 36 KB
    __shared__ unsigned short whbuf[CAP2];// 18 KB
    __shared__ int hist[NBIN2];
    __shared__ int binoff[NBIN2];
    __shared__ int s[NBIN2];
    __shared__ float wd[NBIN2];
    int t = threadIdx.x, b = blockIdx.x;
    int e0 = rpB[b], cnt = rpB[b + 1] - e0;
    if (t < NBIN2) { hist[t] = 0; wd[t] = 0.f; }
    __syncthreads();
    for (int k = t; k < cnt; k += 1024) {
        int u = key4[e0 + k];
        unsigned short wh = wh2[e0 + k];
        keybuf[k] = u; whbuf[k] = wh;
        int dl = ((unsigned)u >> 16) & (BK2_W - 1);
        atomicAdd(&hist[dl], 1);
        atomicAdd(&wd[dl], __half2float(__ushort_as_half(wh)));
    }
    __syncthreads();
    if (t < NBIN2) s[t] = hist[t];
    __syncthreads();
    for (int off = 1; off < NBIN2; off <<= 1) {
        int a = (t < NBIN2 && t >= off) ? s[t - off] : 0;
        __syncthreads();
        if (t < NBIN2) s[t] += a;
        __syncthreads();
    }
    if (t < NBIN2) {
        binoff[t] = s[t] - hist[t];      // exclusive
        int node = (b << BK2_SHIFT) + t;
        if (node < N_NODES) {
            rp2[node]  = e0 + s[t] - hist[t];
            rp2e[node] = e0 + s[t];
            float di = rsqrtf(1.0f + wd[t]);
            dinv[node] = di;
            const float* xi = &x[node * IN_F];
            __half* o = &xp[node * 8];
#pragma unroll
            for (int f = 0; f < IN_F; ++f) o[f] = __float2half(xi[f] * di);
            o[5] = o[6] = o[7] = __float2half(0.f);
        }
    }
    __syncthreads();
    for (int k = t; k < cnt; k += 1024) {
        int u = keybuf[k];
        int dl = ((unsigned)u >> 16) & (BK2_W - 1);
        int pos = atomicAdd(&binoff[dl], 1);
        key4[e0 + pos] = (u & 0xFFFF) | ((int)whbuf[k] << 16);   // {src | fp16 w}
    }
}

// ---------- layer-1 gather: p = di*(sum w*xp[s] + xp[node]) ----------
__global__ void k_p(const int* rp2, const int* rp2e, const int* pk,
                    const __half* xp, const float* dinv, float* p) {
    int node = blockIdx.x * 4 + (threadIdx.x >> 6);
    int lane = threadIdx.x & 63;
    if (node >= N_NODES) return;
    int b = rp2[node], en = rp2e[node];
    float a0 = 0.f, a1 = 0.f, a2 = 0.f, a3 = 0.f, a4 = 0.f;
    for (int k = b + lane; k < en; k += 64) {
        int e = pk[k];
        float w = __half2float(__ushort_as_half((unsigned short)((unsigned)e >> 16)));
        const __half* xs = &xp[(e & 0xFFFF) * 8];
        int4 xv = *reinterpret_cast<const int4*>(xs);
        __half2 p01 = *(__half2*)&xv.x;
        __half2 p23 = *(__half2*)&xv.y;
        __half2 p45 = *(__half2*)&xv.z;
        a0 += w * __half2float(p01.x); a1 += w * __half2float(p01.y);
        a2 += w * __half2float(p23.x); a3 += w * __half2float(p23.y);
        a4 += w * __half2float(p45.x);
    }
    for (int off = 32; off; off >>= 1) {
        a0 += __shfl_down(a0, off); a1 += __shfl_down(a1, off); a2 += __shfl_down(a2, off);
        a3 += __shfl_down(a3, off); a4 += __shfl_down(a4, off);
    }
    if (lane == 0) {
        float di = dinv[node];
        const __half* xn = &xp[node * 8];
        float* pp = &p[node * IN_F];
        pp[0] = di * (a0 + __half2float(xn[0]));
        pp[1] = di * (a1 + __half2float(xn[1]));
        pp[2] = di * (a2 + __half2float(xn[2]));
        pp[3] = di * (a3 + __half2float(xn[3]));
        pp[4] = di * (a4 + __half2float(xn[4]));
    }
}

// ---------- fused h1 = relu(p@W1+b1); g' = (h1@W2)*dinv -> biased-u8/row + scale ----------
__global__ void k_h1g(const float* p, const float* W1, const float* b1,
                      const float* W2, const float* dinv,
                      unsigned char* g8u, float* rs) {
    __shared__ float W1s[IN_F * HID];
    __shared__ float W2s[HID * HID];
    __shared__ float b1s[HID];
    int t = threadIdx.x;
    for (int k = t; k < IN_F * HID; k += 256) W1s[k] = W1[k];
    for (int k = t; k < HID * HID; k += 256) W2s[k] = W2[k];
    if (t < HID) b1s[t] = b1[t];
    __syncthreads();
    int lane = t & 63;
    int wid = blockIdx.x * 4 + (t >> 6);
    int nw = gridDim.x * 4;
    for (int node = wid; node < N_NODES; node += nw) {
        const float* pp = &p[node * IN_F];
        float pv0 = pp[0], pv1 = pp[1], pv2 = pp[2], pv3 = pp[3], pv4 = pp[4];
        float h = b1s[lane] + pv0 * W1s[lane] + pv1 * W1s[64 + lane] + pv2 * W1s[128 + lane]
                + pv3 * W1s[192 + lane] + pv4 * W1s[256 + lane];
        h = fmaxf(h, 0.f);
        float acc = 0.f;
#pragma unroll
        for (int f = 0; f < HID; ++f) {
            float hf = __int_as_float(__builtin_amdgcn_readlane(__float_as_int(h), f));
            acc += hf * W2s[f * HID + lane];
        }
        float gv = acc * dinv[node];                 // g' value
        float am = fabsf(gv);
        for (int off = 32; off; off >>= 1) am = fmaxf(am, __shfl_xor(am, off));
        float inv = (am > 0.f) ? 127.0f / am : 0.f;
        g8u[node * HID + lane] = (unsigned char)(__float2int_rn(gv * inv) + 128);
        if (lane == 0) rs[node] = (am > 0.f) ? am * (1.0f / 127.0f) : 0.f;
    }
}

// ---------- layer-2: dword gather (4 feats/lane, 4 edges/wave) + bias/relu/pool ----------
#define EDGE4_BODY(UU)                                                         \
    {                                                                          \
        int u_ = (UU);                                                         \
        float w_ = __half2float(__ushort_as_half((unsigned short)((unsigned)u_ >> 16))); \
        float wwv_ = w_ * rs[u_ & 0xFFFF];                                     \
        unsigned dw_ = *(const unsigned*)&g8u[(u_ & 0xFFFF) * HID + fo];       \
        a0 += wwv_ * (float)(dw_ & 0xFF);                                      \
        a1 += wwv_ * (float)((dw_ >> 8) & 0xFF);                               \
        a2 += wwv_ * (float)((dw_ >> 16) & 0xFF);                              \
        a3 += wwv_ * (float)(dw_ >> 24);                                       \
        sww += wwv_;                                                           \
    }

__global__ __launch_bounds__(256, 8) void k_h2g(const int* rp2, const int* rp2e,
                      const int* pk, const float* dinv, const unsigned char* g8u,
                      const float* rs, const float* b2, const int* batch, float* pool) {
    int t = threadIdx.x, lane = t & 63;
    int grp = lane >> 4;                 // edge sub-group 0..3
    int fo = (lane & 15) << 2;           // feature offset 0..60
    int wid = blockIdx.x * 4 + (t >> 6);
    int n0 = (int)(((long long)wid * N_NODES) / NWAVE);
    int n1 = (int)(((long long)(wid + 1) * N_NODES) / NWAVE);
    if (n0 >= n1) return;
    float4 bj = *reinterpret_cast<const float4*>(&b2[fo]);
    float p0 = 0.f, p1 = 0.f, p2 = 0.f, p3 = 0.f;
    int cur = batch[n0];
    for (int node = n0; node < n1; ++node) {
        // self-loop, quarter-weighted (x4 across groups = exact)
        unsigned dws = *(const unsigned*)&g8u[node * HID + fo];
        float wq4 = 0.25f * rs[node];
        float a0 = wq4 * (float)(dws & 0xFF);
        float a1 = wq4 * (float)((dws >> 8) & 0xFF);
        float a2 = wq4 * (float)((dws >> 16) & 0xFF);
        float a3 = wq4 * (float)(dws >> 24);
        float sww = wq4;
        for (int k0 = rp2[node], e1 = rp2e[node]; k0 < e1; k0 += 64) {
            int kk = k0 + lane;
            int ev = (kk < e1) ? pk[kk] : 0;          // pad: src=0, w=+0.0
            int m = e1 - k0; if (m > 64) m = 64;
            if (m == 64) {
#pragma unroll
                for (int q = 0; q < 16; ++q) EDGE4_BODY(__shfl(ev, (q << 2) | grp))
            } else {
                int ng = (m + 3) >> 2;
                for (int q = 0; q < ng; ++q) EDGE4_BODY(__shfl(ev, (q << 2) | grp))
            }
        }
        // reduce across the 4 groups
#pragma unroll
        for (int off = 16; off <= 32; off <<= 1) {
            a0 += __shfl_xor(a0, off); a1 += __shfl_xor(a1, off);
            a2 += __shfl_xor(a2, off); a3 += __shfl_xor(a3, off);
            sww += __shfl_xor(sww, off);
        }
        float di = dinv[node];
        float corr = 128.0f * sww;
        float h0 = fmaxf(di * (a0 - corr) + bj.x, 0.f);
        float h1 = fmaxf(di * (a1 - corr) + bj.y, 0.f);
        float h2 = fmaxf(di * (a2 - corr) + bj.z, 0.f);
        float h3 = fmaxf(di * (a3 - corr) + bj.w, 0.f);
        int bb = batch[node];
        if (bb != cur) {
            if (lane < 16) {
                float* pb = &pool[cur * HID + fo];
                atomicAdd(pb + 0, p0); atomicAdd(pb + 1, p1);
                atomicAdd(pb + 2, p2); atomicAdd(pb + 3, p3);
            }
            cur = bb;
            p0 = p1 = p2 = p3 = 0.f;
        }
        p0 += h0; p1 += h1; p2 += h2; p3 += h3;
    }
    if (lane < 16) {
        float* pb = &pool[cur * HID + fo];
        atomicAdd(pb + 0, p0); atomicAdd(pb + 1, p1);
        atomicAdd(pb + 2, p2); atomicAdd(pb + 3, p3);
    }
}

__device__ int lowb(const int* a, int n, int v) {
    int lo = 0, hi = n;
    while (lo < hi) { int m = (lo + hi) >> 1; if (a[m] < v) lo = m + 1; else hi = m; }
    return lo;
}

__global__ void k_out(const float* pool, const int* batch, const float* Wo,
                      const float* bo, float* out) {
    int t = blockIdx.x * blockDim.x + threadIdx.x;
    if (t < N_GRAPHS * OUT_F) {
        int gi = t / OUT_F, k = t % OUT_F;
        int c = lowb(batch, N_NODES, gi + 1) - lowb(batch, N_NODES, gi);
        float cf = fmaxf((float)c, 1.0f);
        float acc = bo[k];
        for (int f = 0; f < HID; ++f)
            acc += (pool[gi * HID + f] / cf) * Wo[f * OUT_F + k];
        out[t] = acc;
    }
}

extern "C" void kernel_launch(void* const* d_in, const int* in_sizes, int n_in,
                              void* d_out, int out_size, void* d_ws, size_t ws_size,
                              hipStream_t stream) {
    const float* x   = (const float*)d_in[0];
    const int*   ei  = (const int*)d_in[1];
    const float* ea  = (const float*)d_in[2];
    const int*   bat = (const int*)d_in[3];
    const float* W1  = (const float*)d_in[4];
    const float* b1  = (const float*)d_in[5];
    const float* W2  = (const float*)d_in[6];
    const float* b2  = (const float*)d_in[7];
    const float* Wo  = (const float*)d_in[8];
    const float* bo  = (const float*)d_in[9];
    float* out = (float*)d_out;

    const int* src = ei;
    const int* dst = ei + N_EDGES;

    // workspace layout (float units) — total 6,254,464 floats = 25.0 MB
    float* ws = (float*)d_ws;
    int*   rpB    = (int*)ws;                        // 392 (pad 400)
    int*   cursor = (int*)(ws + 400);                // 391 (pad 400)
    int*   rp2    = (int*)(ws + 800);                // 50000 (pad 50016)
    int*   rp2e   = (int*)(ws + 50816);              // 50000 (pad 50016)
    float* dinv   = ws + 100832;                     // 50000 (pad 50016)
    float* rs     = ws + 150848;                     // 50000 (pad 50016)
    float* pool   = ws + 200864;                     // 3200
    int*   total  = (int*)(ws + 204064);             // 391 (pad 400)
    float* p      = ws + 204464;                     // 250000
    int*   key4   = (int*)(ws + 454464);             // 3.2M ints; packed pk after k_bsort2
    unsigned short* wh2 = (unsigned short*)(ws + 3654464);  // 3.2M u16 = 1.6M floats
    unsigned char* g8u = (unsigned char*)(ws + 5254464);    // 3.2MB = 800000 floats
    __half* xp    = (__half*)(ws + 6054464);         // 400000 halves = 200000 floats

    hipMemsetAsync(total, 0, NBKT2 * sizeof(int), stream);
    hipMemsetAsync(pool, 0, N_GRAPHS * HID * sizeof(float), stream);

    k_bhist <<<NB1, 1024, 0, stream>>>(dst, total);
    k_bscanB<<<1, 256, 0, stream>>>(total, rpB, cursor);
    k_bucket<<<NB1, 1024, 0, stream>>>(src, dst, ea, cursor, key4, wh2);
    k_bsort2<<<NBKT2, 1024, 0, stream>>>(rpB, key4, wh2, x, rp2, rp2e, dinv, xp);
    k_p     <<<(N_NODES + 3) / 4, 256, 0, stream>>>(rp2, rp2e, key4, xp, dinv, p);
    k_h1g   <<<1024, 256, 0, stream>>>(p, W1, b1, W2, dinv, g8u, rs);
    k_h2g   <<<NWAVE / 4, 256, 0, stream>>>(rp2, rp2e, key4, dinv, g8u, rs, b2, bat, pool);
    k_out   <<<1, 128, 0, stream>>>(pool, bat, Wo, bo, out);
}

// Round 15
// 281.480 us; speedup vs baseline: 1.0842x; 1.0240x over previous
//
#include <hip/hip_runtime.h>
#include <hip/hip_fp16.h>

#define N_NODES 50000
#define N_EDGES 3200000
#define N_GRAPHS 50
#define IN_F 5
#define HID 64
#define OUT_F 2

#define BK2_SHIFT 7
#define BK2_W 128                      // nodes per bucket
#define NBKT2 391                      // ceil(50000/128)
#define NB_BH 250                      // bhist blocks
#define EPB_BH 12800                   // edges per bhist block
#define NB_BK 500                      // bucket blocks (1 tile each)
#define TILE 6400                      // edges staged in LDS per bucket block
#define SLOTS 7                        // ceil(TILE/1024)
#define CAP2 9216                      // max edges/bucket (mean 8192, +11 sigma)
#define NBIN2 128                      // sort bins (dst_local)
#define NWAVE 8192                     // k_h2g waves (2048 blocks, all co-resident)

// ---------- global per-bucket totals (LDS-aggregated histogram) ----------
__global__ __launch_bounds__(1024) void k_bhist(const int* dst, int* total) {
    __shared__ int hist[NBKT2];
    int t = threadIdx.x, blk = blockIdx.x;
    for (int b = t; b < NBKT2; b += 1024) hist[b] = 0;
    __syncthreads();
    int base = blk * EPB_BH;
    for (int k = t; k < EPB_BH; k += 1024)
        atomicAdd(&hist[__builtin_nontemporal_load(&dst[base + k]) >> BK2_SHIFT], 1);
    __syncthreads();
    for (int b = t; b < NBKT2; b += 1024) {
        int h = hist[b];
        if (h) atomicAdd(&total[b], h);
    }
}

// ---------- exclusive scan of 391 totals -> rpB, cursor ----------
__global__ void k_bscanB(const int* total, int* rpB, int* cursor) {
    __shared__ int s[256];
    int t = threadIdx.x;
    int v[2], sum = 0;
#pragma unroll
    for (int j = 0; j < 2; ++j) {
        int idx = t * 2 + j;
        v[j] = (idx < NBKT2) ? total[idx] : 0;
        sum += v[j];
    }
    s[t] = sum;
    __syncthreads();
    for (int off = 1; off < 256; off <<= 1) {
        int a = (t >= off) ? s[t - off] : 0;
        __syncthreads();
        s[t] += a;
        __syncthreads();
    }
    int run = s[t] - sum;
#pragma unroll
    for (int j = 0; j < 2; ++j) {
        int idx = t * 2 + j;
        if (idx < NBKT2) { rpB[idx] = run; cursor[idx] = run; }
        run += v[j];
    }
    if (t == 0) rpB[NBKT2] = N_EDGES;
}

// ---------- LDS-staged bucket scatter: burst-contiguous chunk writes ----------
__global__ __launch_bounds__(1024) void k_bucket(const int* src, const int* dst,
                        const float* ew, int* cursor, int* key4, unsigned short* wh2) {
    __shared__ int keyb[TILE];             // 25.6 KB
    __shared__ unsigned short whb[TILE];   // 12.8 KB
    __shared__ int hist[NBKT2];
    __shared__ int soff[NBKT2];
    __shared__ int delta[NBKT2];
    __shared__ int s[512];
    int t = threadIdx.x;
    int base = blockIdx.x * TILE;
    for (int b = t; b < NBKT2; b += 1024) hist[b] = 0;
    __syncthreads();
    int ky[SLOTS]; unsigned short wv[SLOTS]; int rk[SLOTS];
#pragma unroll
    for (int i = 0; i < SLOTS; ++i) {
        int k = t + i * 1024;
        if (k < TILE) {
            int d  = __builtin_nontemporal_load(&dst[base + k]);
            int sv = __builtin_nontemporal_load(&src[base + k]);
            float w = __builtin_nontemporal_load(&ew[base + k]);
            ky[i] = sv | (d << 16);
            wv[i] = __half_as_ushort(__float2half(w));
            rk[i] = atomicAdd(&hist[d >> BK2_SHIFT], 1);
        }
    }
    __syncthreads();
    if (t < 512) s[t] = (t < NBKT2) ? hist[t] : 0;
    __syncthreads();
    for (int off = 1; off < 512; off <<= 1) {
        int a = (t < 512 && t >= off) ? s[t - off] : 0;
        __syncthreads();
        if (t < 512) s[t] += a;
        __syncthreads();
    }
    if (t < NBKT2) {
        int h = hist[t];
        soff[t] = s[t] - h;                       // tile-local exclusive offset
        if (h) delta[t] = atomicAdd(&cursor[t], h) - soff[t];
    }
    __syncthreads();
#pragma unroll
    for (int i = 0; i < SLOTS; ++i) {
        int k = t + i * 1024;
        if (k < TILE) {
            int b = ((unsigned)ky[i] >> 16) >> BK2_SHIFT;
            int p = soff[b] + rk[i];
            keyb[p] = ky[i];
            whb[p] = wv[i];
        }
    }
    __syncthreads();
#pragma unroll
    for (int i = 0; i < SLOTS; ++i) {
        int k = t + i * 1024;
        if (k < TILE) {
            int u = keyb[k];
            int b = ((unsigned)u >> 16) >> BK2_SHIFT;
            int gp = k + delta[b];
            key4[gp] = u;
            wh2[gp] = whb[k];
        }
    }
}

// ---------- phase 2: 128-bin sort per bucket; emits pk (over key4), rp2, dinv, xp ----------
__global__ __launch_bounds__(1024) void k_bsort2(const int* rpB, int* key4,
                      const unsigned short* wh2, const float* x,
                      int* rp2, float* dinv, __half* xp) {
    __shared__ int keybuf[CAP2];          // 36 KB
    __shared__ unsigned short whbuf[CAP2];// 18 KB
    __shared__ int hist[NBIN2];
    __shared__ int binoff[NBIN2];
    __shared__ int s[NBIN2];
    __shared__ float wd[NBIN2];
    int t = threadIdx.x, b = blockIdx.x;
    int e0 = rpB[b], cnt = rpB[b + 1] - e0;
    if (t < NBIN2) { hist[t] = 0; wd[t] = 0.f; }
    __syncthreads();
    for (int k = t; k < cnt; k += 1024) {
        int u = key4[e0 + k];
        unsigned short wh = wh2[e0 + k];
        keybuf[k] = u; whbuf[k] = wh;
        int dl = ((unsigned)u >> 16) & (BK2_W - 1);
        atomicAdd(&hist[dl], 1);
        atomicAdd(&wd[dl], __half2float(__ushort_as_half(wh)));
    }
    __syncthreads();
    if (t < NBIN2) s[t] = hist[t];
    __syncthreads();
    for (int off = 1; off < NBIN2; off <<= 1) {
        int a = (t < NBIN2 && t >= off) ? s[t - off] : 0;
        __syncthreads();
        if (t < NBIN2) s[t] += a;
        __syncthreads();
    }
    if (t < NBIN2) {
        binoff[t] = s[t] - hist[t];      // exclusive
        int node = (b << BK2_SHIFT) + t;
        if (node < N_NODES) {
            rp2[node] = e0 + s[t] - hist[t];
            float di = rsqrtf(1.0f + wd[t]);
            dinv[node] = di;
            const float* xi = &x[node * IN_F];
            __half* o = &xp[node * 8];
#pragma unroll
            for (int f = 0; f < IN_F; ++f) o[f] = __float2half(xi[f] * di);
            o[5] = o[6] = o[7] = __float2half(0.f);
        }
    }
    if (b == NBKT2 - 1 && t == 0) rp2[N_NODES] = N_EDGES;
    __syncthreads();                     // rp2 reads binoff before cursors mutate
    for (int k = t; k < cnt; k += 1024) {
        int u = keybuf[k];
        int dl = ((unsigned)u >> 16) & (BK2_W - 1);
        int pos = atomicAdd(&binoff[dl], 1);
        key4[e0 + pos] = (u & 0xFFFF) | ((int)whbuf[k] << 16);   // {src | fp16 w}
    }
}

// ---------- fused layer-1: gather + W1 relu + W2 + int8 quantize (p never stored) ----------
__global__ __launch_bounds__(256) void k_ph1g(const int* rp2, const int* pk,
                      const __half* xp, const float* dinv, const float* W1,
                      const float* b1, const float* W2,
                      unsigned char* g8u, float* rs) {
    __shared__ float W1s[IN_F * HID];
    __shared__ float W2s[HID * HID];
    __shared__ float b1s[HID];
    int t = threadIdx.x;
    for (int k = t; k < IN_F * HID; k += 256) W1s[k] = W1[k];
    for (int k = t; k < HID * HID; k += 256) W2s[k] = W2[k];
    if (t < HID) b1s[t] = b1[t];
    __syncthreads();
    int lane = t & 63;
    int wid = blockIdx.x * 4 + (t >> 6);
    int nw = gridDim.x * 4;
    for (int node = wid; node < N_NODES; node += nw) {
        int b = rp2[node], en = rp2[node + 1];
        float a0 = 0.f, a1 = 0.f, a2 = 0.f, a3 = 0.f, a4 = 0.f;
        for (int k = b + lane; k < en; k += 64) {
            int e = pk[k];
            float w = __half2float(__ushort_as_half((unsigned short)((unsigned)e >> 16)));
            const __half* xs = &xp[(e & 0xFFFF) * 8];
            int4 xv = *reinterpret_cast<const int4*>(xs);
            __half2 p01 = *(__half2*)&xv.x;
            __half2 p23 = *(__half2*)&xv.y;
            __half2 p45 = *(__half2*)&xv.z;
            a0 += w * __half2float(p01.x); a1 += w * __half2float(p01.y);
            a2 += w * __half2float(p23.x); a3 += w * __half2float(p23.y);
            a4 += w * __half2float(p45.x);
        }
        // butterfly -> all lanes hold the sums
        for (int off = 1; off < 64; off <<= 1) {
            a0 += __shfl_xor(a0, off); a1 += __shfl_xor(a1, off);
            a2 += __shfl_xor(a2, off); a3 += __shfl_xor(a3, off);
            a4 += __shfl_xor(a4, off);
        }
        float di = dinv[node];
        const __half* xn = &xp[node * 8];
        float p0 = di * (a0 + __half2float(xn[0]));
        float p1 = di * (a1 + __half2float(xn[1]));
        float p2 = di * (a2 + __half2float(xn[2]));
        float p3 = di * (a3 + __half2float(xn[3]));
        float p4 = di * (a4 + __half2float(xn[4]));
        float h = b1s[lane] + p0 * W1s[lane] + p1 * W1s[64 + lane] + p2 * W1s[128 + lane]
                + p3 * W1s[192 + lane] + p4 * W1s[256 + lane];
        h = fmaxf(h, 0.f);
        float acc = 0.f;
#pragma unroll
        for (int f = 0; f < HID; ++f) {
            float hf = __int_as_float(__builtin_amdgcn_readlane(__float_as_int(h), f));
            acc += hf * W2s[f * HID + lane];
        }
        float gv = acc * di;                         // g' value
        float am = fabsf(gv);
        for (int off = 32; off; off >>= 1) am = fmaxf(am, __shfl_xor(am, off));
        float inv = (am > 0.f) ? 127.0f / am : 0.f;
        g8u[node * HID + lane] = (unsigned char)(__float2int_rn(gv * inv) + 128);
        if (lane == 0) rs[node] = (am > 0.f) ? am * (1.0f / 127.0f) : 0.f;
    }
}

// ---------- layer-2: dword gather + chunk-ahead prefetch + bias/relu/pool ----------
#define EDGE4_BODY_U(UU)                                                       \
    {                                                                          \
        int u_ = (UU);                                                         \
        float w_ = __half2float(__ushort_as_half((unsigned short)((unsigned)u_ >> 16))); \
        float wwv_ = w_ * rs[u_ & 0xFFFF];                                     \
        unsigned dw_ = *(const unsigned*)&g8u[(u_ & 0xFFFF) * HID + fo];       \
        a0 += wwv_ * (float)(dw_ & 0xFF);                                      \
        a1 += wwv_ * (float)((dw_ >> 8) & 0xFF);                               \
        a2 += wwv_ * (float)((dw_ >> 16) & 0xFF);                              \
        a3 += wwv_ * (float)(dw_ >> 24);                                       \
        sww += wwv_;                                                           \
    }

__global__ __launch_bounds__(256, 8) void k_h2g(const int* rp2,
                      const int* pk, const float* dinv, const unsigned char* g8u,
                      const float* rs, const float* b2, const int* batch, float* pool) {
    int t = threadIdx.x, lane = t & 63;
    int grp = lane >> 4;                 // edge sub-group 0..3
    int fo = (lane & 15) << 2;           // feature offset 0..60
    int wid = blockIdx.x * 4 + (t >> 6);
    int n0 = (int)(((long long)wid * N_NODES) / NWAVE);
    int n1 = (int)(((long long)(wid + 1) * N_NODES) / NWAVE);
    if (n0 >= n1) return;
    float4 bj = *reinterpret_cast<const float4*>(&b2[fo]);
    float p0 = 0.f, p1 = 0.f, p2 = 0.f, p3 = 0.f;
    int cur = batch[n0];
    int span_end = rp2[n1];
    int kcur = rp2[n0];
    int kk0 = kcur + lane;
    int ev = (kk0 < N_EDGES) ? pk[kk0] : 0;          // prefetched first chunk
    for (int node = n0; node < n1; ++node) {
        int e1 = rp2[node + 1];
        // self-loop, quarter-weighted (x4 across groups = exact)
        unsigned dws = *(const unsigned*)&g8u[node * HID + fo];
        float wq4 = 0.25f * rs[node];
        float a0 = wq4 * (float)(dws & 0xFF);
        float a1 = wq4 * (float)((dws >> 8) & 0xFF);
        float a2 = wq4 * (float)((dws >> 16) & 0xFF);
        float a3 = wq4 * (float)(dws >> 24);
        float sww = wq4;
        while (kcur < e1) {
            int m = e1 - kcur; if (m > 64) m = 64;
            int knext = kcur + m;
            int evn = 0;
            if (knext < span_end) {                  // issue next-chunk load early
                int kk2 = knext + lane;
                evn = (kk2 < N_EDGES) ? pk[kk2] : 0;
            }
            if (m == 64) {
#pragma unroll
                for (int q = 0; q < 16; ++q) {
                    int u = __shfl(ev, (q << 2) | grp);
                    EDGE4_BODY_U(u)
                }
            } else {
                int ng = (m + 3) >> 2;
                for (int q = 0; q < ng; ++q) {
                    int slot = (q << 2) | grp;
                    int u = __shfl(ev, slot);
                    if (slot >= m) u = 0;            // mask overhang (next node's edges)
                    EDGE4_BODY_U(u)
                }
            }
            ev = evn; kcur = knext;
        }
        // reduce across the 4 groups
#pragma unroll
        for (int off = 16; off <= 32; off <<= 1) {
            a0 += __shfl_xor(a0, off); a1 += __shfl_xor(a1, off);
            a2 += __shfl_xor(a2, off); a3 += __shfl_xor(a3, off);
            sww += __shfl_xor(sww, off);
        }
        float di = dinv[node];
        float corr = 128.0f * sww;
        float h0 = fmaxf(di * (a0 - corr) + bj.x, 0.f);
        float h1 = fmaxf(di * (a1 - corr) + bj.y, 0.f);
        float h2 = fmaxf(di * (a2 - corr) + bj.z, 0.f);
        float h3 = fmaxf(di * (a3 - corr) + bj.w, 0.f);
        int bb = batch[node];
        if (bb != cur) {
            if (lane < 16) {
                float* pb = &pool[cur * HID + fo];
                atomicAdd(pb + 0, p0); atomicAdd(pb + 1, p1);
                atomicAdd(pb + 2, p2); atomicAdd(pb + 3, p3);
            }
            cur = bb;
            p0 = p1 = p2 = p3 = 0.f;
        }
        p0 += h0; p1 += h1; p2 += h2; p3 += h3;
    }
    if (lane < 16) {
        float* pb = &pool[cur * HID + fo];
        atomicAdd(pb + 0, p0); atomicAdd(pb + 1, p1);
        atomicAdd(pb + 2, p2); atomicAdd(pb + 3, p3);
    }
}

__device__ int lowb(const int* a, int n, int v) {
    int lo = 0, hi = n;
    while (lo < hi) { int m = (lo + hi) >> 1; if (a[m] < v) lo = m + 1; else hi = m; }
    return lo;
}

__global__ void k_out(const float* pool, const int* batch, const float* Wo,
                      const float* bo, float* out) {
    int t = blockIdx.x * blockDim.x + threadIdx.x;
    if (t < N_GRAPHS * OUT_F) {
        int gi = t / OUT_F, k = t % OUT_F;
        int c = lowb(batch, N_NODES, gi + 1) - lowb(batch, N_NODES, gi);
        float cf = fmaxf((float)c, 1.0f);
        float acc = bo[k];
        for (int f = 0; f < HID; ++f)
            acc += (pool[gi * HID + f] / cf) * Wo[f * OUT_F + k];
        out[t] = acc;
    }
}

extern "C" void kernel_launch(void* const* d_in, const int* in_sizes, int n_in,
                              void* d_out, int out_size, void* d_ws, size_t ws_size,
                              hipStream_t stream) {
    const float* x   = (const float*)d_in[0];
    const int*   ei  = (const int*)d_in[1];
    const float* ea  = (const float*)d_in[2];
    const int*   bat = (const int*)d_in[3];
    const float* W1  = (const float*)d_in[4];
    const float* b1  = (const float*)d_in[5];
    const float* W2  = (const float*)d_in[6];
    const float* b2  = (const float*)d_in[7];
    const float* Wo  = (const float*)d_in[8];
    const float* bo  = (const float*)d_in[9];
    float* out = (float*)d_out;

    const int* src = ei;
    const int* dst = ei + N_EDGES;

    // workspace layout (float units) — total 5,954,448 floats = 23.8 MB
    float* ws = (float*)d_ws;
    int*   rpB    = (int*)ws;                        // 392 (pad 400)
    int*   cursor = (int*)(ws + 400);                // 391 (pad 400)
    int*   rp2    = (int*)(ws + 800);                // 50001 (pad 50016)
    float* dinv   = ws + 50816;                      // 50000 (pad 50016)
    float* rs     = ws + 100832;                     // 50000 (pad 50016)
    float* pool   = ws + 150848;                     // 3200
    int*   total  = (int*)(ws + 154048);             // 391 (pad 400)
    int*   key4   = (int*)(ws + 154448);             // 3.2M ints; packed pk after k_bsort2
    unsigned short* wh2 = (unsigned short*)(ws + 3354448);  // 3.2M u16 = 1.6M floats
    unsigned char* g8u = (unsigned char*)(ws + 4954448);    // 3.2MB = 800000 floats
    __half* xp    = (__half*)(ws + 5754448);         // 400000 halves = 200000 floats

    hipMemsetAsync(total, 0, NBKT2 * sizeof(int), stream);
    hipMemsetAsync(pool, 0, N_GRAPHS * HID * sizeof(float), stream);

    k_bhist <<<NB_BH, 1024, 0, stream>>>(dst, total);
    k_bscanB<<<1, 256, 0, stream>>>(total, rpB, cursor);
    k_bucket<<<NB_BK, 1024, 0, stream>>>(src, dst, ea, cursor, key4, wh2);
    k_bsort2<<<NBKT2, 1024, 0, stream>>>(rpB, key4, wh2, x, rp2, dinv, xp);
    k_ph1g  <<<2048, 256, 0, stream>>>(rp2, key4, xp, dinv, W1, b1, W2, g8u, rs);
    k_h2g   <<<NWAVE / 4, 256, 0, stream>>>(rp2, key4, dinv, g8u, rs, b2, bat, pool);
    k_out   <<<1, 128, 0, stream>>>(pool, bat, Wo, bo, out);
}